// Round 1
// baseline (343.608 us; speedup 1.0000x reference)
//
#include <hip/hip_runtime.h>

typedef unsigned short ushort_t;
typedef _Float16 half8 __attribute__((ext_vector_type(8)));
typedef short short8 __attribute__((ext_vector_type(8)));
typedef float floatx4 __attribute__((ext_vector_type(4)));

#define NCC 65536
#define NPP 1024
#define DD 256

static __device__ __forceinline__ ushort_t f2h_bits(float x) {
  _Float16 h = (_Float16)x;
  return __builtin_bit_cast(ushort_t, h);
}
static __device__ __forceinline__ ushort_t f2bf_bits(float x) {
  unsigned u = __builtin_bit_cast(unsigned, x);
  unsigned r = (u + 0x7FFFu + ((u >> 16) & 1u)) >> 16;
  return (ushort_t)r;
}
static __device__ __forceinline__ unsigned pack2h(float a, float b) {
  return (unsigned)f2h_bits(a) | ((unsigned)f2h_bits(b) << 16);
}

// ---------------------------------------------------------------------------
// K1: fused GEMM producing keyf (scaled) and query, both f16, via MFMA.
// blocks 0..1023: keyf rows (also writes xs/ys); blocks 1024..1039: query rows.
// ---------------------------------------------------------------------------
__global__ __launch_bounds__(256) void prep_gemm(
    const float* __restrict__ box_feat, const float* __restrict__ points_feat,
    const float* __restrict__ centers, const float* __restrict__ scales,
    const float* __restrict__ Wq, const float* __restrict__ bq,
    const float* __restrict__ Wk, const float* __restrict__ bk,
    ushort_t* __restrict__ q_out, ushort_t* __restrict__ kf_out,
    float* __restrict__ xs, float* __restrict__ ys) {
  __shared__ __align__(16) ushort_t lds_a[64][264];  // A rows (m=64, k=256), pad 8
  __shared__ __align__(16) ushort_t lds_b[64][136];  // W^T panel (n=64, k=128), pad 8
  __shared__ float lds_s[64];

  const int t = threadIdx.x;
  const bool isQ = (blockIdx.x >= (NCC / 64));
  const int row0 = isQ ? ((int)blockIdx.x - NCC / 64) * 64 : (int)blockIdx.x * 64;
  const float* In = isQ ? points_feat : box_feat;
  const float* W = isQ ? Wq : Wk;
  const float* Bi = isQ ? bq : bk;
  ushort_t* Out = isQ ? q_out : kf_out;

  if (t < 64) {
    float s = 1.0f;
    if (!isQ) {
      int c = row0 + t;
      float stride = centers[c * 4 + 3];
      int lvl = (int)(log2f(stride) + 0.5f) - 3;
      lvl = lvl < 0 ? 0 : (lvl > 4 ? 4 : lvl);
      s = scales[lvl];
      float hf = floorf(centers[c * 4 + 2] * 0.5f);
      ys[c] = centers[c * 4 + 0] + hf;
      xs[c] = centers[c * 4 + 1] + hf;
    }
    lds_s[t] = s;
  }
  __syncthreads();

  // stage A: 64 rows x 256 cols fp32 -> scaled f16
#pragma unroll
  for (int i = 0; i < 16; i++) {
    int f = t + 256 * i;
    int r = f >> 6;
    int c4 = (f & 63) * 4;
    const float4 v = *(const float4*)&In[(size_t)(row0 + r) * DD + c4];
    float s = lds_s[r];
    *(uint2*)&lds_a[r][c4] = make_uint2(pack2h(v.x * s, v.y * s), pack2h(v.z * s, v.w * s));
  }
  __syncthreads();

  const int w = t >> 6, lane = t & 63, qd = lane >> 4, n = lane & 15;

  for (int g = 0; g < 4; ++g) {
    floatx4 acc[4] = {};
    for (int kh = 0; kh < 2; ++kh) {
      __syncthreads();
      // stage W^T panel: W[k=kh*128..+128][n=g*64..+64] -> lds_b[n][k]
#pragma unroll
      for (int i = 0; i < 8; i++) {
        int f = t + 256 * i;
        int k = f >> 4;
        int j = (f & 15) * 4;
        const float4 v = *(const float4*)&W[(size_t)(kh * 128 + k) * DD + g * 64 + j];
        lds_b[j + 0][k] = f2h_bits(v.x);
        lds_b[j + 1][k] = f2h_bits(v.y);
        lds_b[j + 2][k] = f2h_bits(v.z);
        lds_b[j + 3][k] = f2h_bits(v.w);
      }
      __syncthreads();
#pragma unroll
      for (int s = 0; s < 4; s++) {
        half8 af = __builtin_bit_cast(half8, *(const uint4*)&lds_a[w * 16 + n][kh * 128 + s * 32 + qd * 8]);
#pragma unroll
        for (int nt = 0; nt < 4; ++nt) {
          half8 bf = __builtin_bit_cast(half8, *(const uint4*)&lds_b[nt * 16 + n][s * 32 + qd * 8]);
          acc[nt] = __builtin_amdgcn_mfma_f32_16x16x32_f16(af, bf, acc[nt], 0, 0, 0);
        }
      }
    }
    // epilogue: C/D layout row=4*qd+r, col=lane&15
#pragma unroll
    for (int nt = 0; nt < 4; ++nt) {
#pragma unroll
      for (int r = 0; r < 4; r++) {
        int row = row0 + w * 16 + qd * 4 + r;
        int col = g * 64 + nt * 16 + n;
        Out[(size_t)row * DD + col] = f2h_bits(acc[nt][r] + Bi[col]);
      }
    }
  }
}

// ---------------------------------------------------------------------------
// K2: transpose box_feat (fp32 [NC][256]) -> vT (bf16 [256][NC])
// ---------------------------------------------------------------------------
__global__ __launch_bounds__(256) void transpose_v(const float* __restrict__ box_feat,
                                                   ushort_t* __restrict__ vT) {
  __shared__ __align__(16) ushort_t lt[64][72];
  const int t = threadIdx.x;
  const int c0 = blockIdx.x * 64, d0 = blockIdx.y * 64;
#pragma unroll
  for (int i = 0; i < 4; i++) {
    int f = t + 256 * i;
    int c = f >> 4;
    int j = (f & 15) * 4;
    const float4 v = *(const float4*)&box_feat[(size_t)(c0 + c) * DD + d0 + j];
    lt[j + 0][c] = f2bf_bits(v.x);
    lt[j + 1][c] = f2bf_bits(v.y);
    lt[j + 2][c] = f2bf_bits(v.z);
    lt[j + 3][c] = f2bf_bits(v.w);
  }
  __syncthreads();
#pragma unroll
  for (int i = 0; i < 4; i++) {
    int f = t + 256 * i;
    int d = f >> 4;
    int j = (f & 15) * 4;
    *(uint2*)&vT[(size_t)(d0 + d) * NCC + c0 + j] = *(uint2*)&lt[d][j];
  }
}

// ---------------------------------------------------------------------------
// K3: fused attention. Block = 4 waves x 16 points = 64 points; loops over a
// 2048-candidate chunk in sub-tiles of 32. QK^T via f16 MFMA, fixed-base-50
// exp (bf16-safe range), PV via bf16 MFMA. Partials -> global atomics.
// ---------------------------------------------------------------------------
__global__ __launch_bounds__(256) void attn_kernel(
    const ushort_t* __restrict__ qf16, const ushort_t* __restrict__ kf16,
    const ushort_t* __restrict__ vT, const float* __restrict__ xs,
    const float* __restrict__ ys, const float* __restrict__ boxes,
    float* __restrict__ acc_out, float* __restrict__ den_out) {
  __shared__ __align__(16) ushort_t lds_k[32][264];    // keyf tile [c][k], pad 8
  __shared__ __align__(16) ushort_t lds_v[256][40];    // vT tile [d][c], pad 8
  __shared__ __align__(16) float2 lds_xy[32];          // (xs, ys) per candidate
  __shared__ __align__(16) ushort_t lds_p[4][16][40];  // per-wave P^T [p][c] bf16

  const int t = threadIdx.x;
  const int w = t >> 6, lane = t & 63, qd = lane >> 4, n = lane & 15;
  const int p0 = blockIdx.x * 64 + w * 16;
  const int p = p0 + n;
  const int cchunk = blockIdx.y * 2048;

  // resident query B-frags: lane holds query[p=n][k=32s+8qd .. +8]
  half8 qfr[8];
#pragma unroll
  for (int s = 0; s < 8; s++)
    qfr[s] = __builtin_bit_cast(half8, *(const uint4*)&qf16[(size_t)p * DD + s * 32 + qd * 8]);

  const float4 bxv = *(const float4*)&boxes[p * 4];  // x1,y1,x2,y2

  floatx4 macc[16] = {};
  float dsum = 0.f;

  for (int it = 0; it < 64; ++it) {
    int cb = cchunk + it * 32;
    // stage keyf tile (32 x 256 f16 = 16KB)
#pragma unroll
    for (int i = 0; i < 4; i++) {
      int f = t + 256 * i;
      int r = f >> 5, sg = (f & 31) * 8;
      *(uint4*)&lds_k[r][sg] = *(const uint4*)&kf16[(size_t)(cb + r) * DD + sg];
    }
    // stage vT tile (256 x 32 bf16 = 16KB)
#pragma unroll
    for (int i = 0; i < 4; i++) {
      int f = t + 256 * i;
      int d = f >> 2, sg = (f & 3) * 8;
      *(uint4*)&lds_v[d][sg] = *(const uint4*)&vT[(size_t)d * NCC + cb + sg];
    }
    if (t < 32) lds_xy[t] = make_float2(xs[cb + t], ys[cb + t]);
    __syncthreads();

    // QK^T: two 16(c) x 16(p) tiles per wave
#pragma unroll
    for (int t2 = 0; t2 < 2; ++t2) {
      floatx4 a = {};
#pragma unroll
      for (int s = 0; s < 8; s++) {
        half8 af = __builtin_bit_cast(half8, *(const uint4*)&lds_k[t2 * 16 + n][s * 32 + qd * 8]);
        a = __builtin_amdgcn_mfma_f32_16x16x32_f16(af, qfr[s], a, 0, 0, 0);
      }
      unsigned pk0 = 0, pk1 = 0;
#pragma unroll
      for (int r = 0; r < 4; r++) {
        int cl = t2 * 16 + qd * 4 + r;  // lane holds sim[c=cl][p=n] in reg r
        float2 xy = lds_xy[cl];
        float l_ = xy.x - bxv.x;
        float t_ = xy.y - bxv.y;
        float r_ = bxv.z - xy.x;
        float b_ = bxv.w - xy.y;
        float mn = fminf(fminf(l_, t_), fminf(r_, b_));
        float sim = fminf(fmaxf(a[r], -50.f), 50.f);
        float e = (mn > 0.f) ? exp2f((sim - 50.f) * 1.44269504f) : 0.f;
        dsum += e;
        unsigned b = (unsigned)f2bf_bits(e);
        if (r == 0) pk0 = b;
        else if (r == 1) pk0 |= b << 16;
        else if (r == 2) pk1 = b;
        else pk1 |= b << 16;
      }
      // P^T to per-wave LDS scratch: row=p-local(n), cols c = t2*16+4qd..+3
      *(uint2*)&lds_p[w][n][t2 * 16 + qd * 4] = make_uint2(pk0, pk1);
    }
    // same-wave LDS RAW: drain our ds_writes before reading lds_p
    __asm__ volatile("s_waitcnt lgkmcnt(0)" ::: "memory");

    // PV: A2 = P^T (m=p, k=c), B2 = V (k=c, n=d) from vT tile
    short8 a2 = __builtin_bit_cast(short8, *(const uint4*)&lds_p[w][n][qd * 8]);
#pragma unroll
    for (int nt = 0; nt < 16; ++nt) {
      short8 b2 = __builtin_bit_cast(short8, *(const uint4*)&lds_v[nt * 16 + n][qd * 8]);
      macc[nt] = __builtin_amdgcn_mfma_f32_16x16x32_bf16(a2, b2, macc[nt], 0, 0, 0);
    }
    __syncthreads();  // protect lds_k/lds_v/lds_xy before next staging
  }

  // denom: lanes l, l^16, l^32, l^48 share the same point column
  dsum += __shfl_xor(dsum, 16, 64);
  dsum += __shfl_xor(dsum, 32, 64);
  if (lane < 16) atomicAdd(&den_out[p0 + n], dsum);

  // merge partials: C/D layout row(p)=4qd+r, col(d)=nt*16+n
#pragma unroll
  for (int nt = 0; nt < 16; ++nt) {
#pragma unroll
    for (int r = 0; r < 4; r++) {
      atomicAdd(&acc_out[(size_t)(p0 + qd * 4 + r) * DD + nt * 16 + n], macc[nt][r]);
    }
  }
}

// ---------------------------------------------------------------------------
// K4: out = points_feat + acc/den (guard empty columns)
// ---------------------------------------------------------------------------
__global__ void finalize(const float* __restrict__ points_feat, const float* __restrict__ acc,
                         const float* __restrict__ den, float* __restrict__ out) {
  int p = blockIdx.x, d = threadIdx.x;
  float dn = den[p];
  float m = (dn > 0.f) ? acc[p * DD + d] / dn : 0.f;
  out[p * DD + d] = points_feat[p * DD + d] + m;
}

extern "C" void kernel_launch(void* const* d_in, const int* in_sizes, int n_in, void* d_out,
                              int out_size, void* d_ws, size_t ws_size, hipStream_t stream) {
  const float* points_feat = (const float*)d_in[0];
  const float* box_feat = (const float*)d_in[1];
  const float* centers = (const float*)d_in[2];
  const float* boxes = (const float*)d_in[3];
  const float* Wq = (const float*)d_in[4];
  const float* bq = (const float*)d_in[5];
  const float* Wk = (const float*)d_in[6];
  const float* bk = (const float*)d_in[7];
  const float* scales = (const float*)d_in[8];

  // workspace layout (~69.2 MB)
  ushort_t* ws_q = (ushort_t*)d_ws;                  // 1024*256 f16
  ushort_t* ws_kf = ws_q + (size_t)NPP * DD;         // 65536*256 f16
  ushort_t* ws_vT = ws_kf + (size_t)NCC * DD;        // 256*65536 bf16
  float* ws_xs = (float*)(ws_vT + (size_t)NCC * DD); // 65536 f32
  float* ws_ys = ws_xs + NCC;                        // 65536 f32
  float* ws_acc = ws_ys + NCC;                       // 1024*256 f32
  float* ws_den = ws_acc + (size_t)NPP * DD;         // 1024 f32

  hipMemsetAsync(ws_acc, 0, ((size_t)NPP * DD + NPP) * sizeof(float), stream);
  prep_gemm<<<NCC / 64 + NPP / 64, 256, 0, stream>>>(box_feat, points_feat, centers, scales, Wq,
                                                     bq, Wk, bk, ws_q, ws_kf, ws_xs, ws_ys);
  transpose_v<<<dim3(NCC / 64, DD / 64), 256, 0, stream>>>(box_feat, ws_vT);
  attn_kernel<<<dim3(NPP / 64, 32), 256, 0, stream>>>(ws_q, ws_kf, ws_vT, ws_xs, ws_ys, boxes,
                                                      ws_acc, ws_den);
  finalize<<<NPP, DD, 0, stream>>>(points_feat, ws_acc, ws_den, (float*)d_out);
}